// Round 8
// baseline (264.095 us; speedup 1.0000x reference)
//
#include <hip/hip_runtime.h>
#include <hip/hip_bf16.h>

// B=4, L=1024, D=1024, H=16, DH=64. Inputs fp32 (proven R0-R4). Output fp32.
// Q pre-scaled by 0.125*log2(e) at proj; pmask pre-scaled by log2(e) at conv.
// Fixed-max exp2 softmax (m=12). attn R8: barrier-free — K/V B-fragments loaded
// directly from global (coalesced 16-row x 64B per dwordx4), LDS only for the
// wave-private P round-trip (row-major stride-136: writer 16 banks, reader at
// the b128 8-access/bank floor). Q-tile 64/block, grid 1024 (4 blocks/CU).
// ws elem offsets (bf16): Q[0,4M) K[4M,8M) V^T[8M,12M) seq@12582912
//   Wq@16777216 Wk@17825792 Wv@18874368 bq@20971520 bk@20972544 bv@20973568 pm@20974592

#define LL 1024

typedef __attribute__((ext_vector_type(8))) short short8;
typedef __attribute__((ext_vector_type(4))) float floatx4;

__device__ __forceinline__ float bf2f(unsigned short u) {
    return __uint_as_float(((unsigned int)u) << 16);
}
__device__ __forceinline__ unsigned short f2bf(float f) {
    unsigned int x = __float_as_uint(f);
    unsigned int r = x + 0x7fffu + ((x >> 16) & 1u);
    return (unsigned short)(r >> 16);
}

#if __has_builtin(__builtin_amdgcn_global_load_lds)
#define HAVE_GLL 1
typedef __attribute__((address_space(1))) unsigned int as1_u32;
typedef __attribute__((address_space(3))) unsigned int as3_u32;
__device__ __forceinline__ void gll16(const void* g, void* l) {
    __builtin_amdgcn_global_load_lds((const as1_u32*)g, (as3_u32*)l, 16, 0, 0);
}
#endif

// ---- fp32 -> clean bf16 conversion, vectorized x8 ----
__global__ __launch_bounds__(256) void conv_in(
    const float* __restrict__ seq, const float* __restrict__ wq,
    const float* __restrict__ wk,  const float* __restrict__ wv,
    const float* __restrict__ bq,  const float* __restrict__ bk,
    const float* __restrict__ bv,  const float* __restrict__ pm,
    unsigned short* __restrict__ ws)
{
    unsigned int t = blockIdx.x * 256u + threadIdx.x;   // grid 3588 -> 918,400 x8
    if (t >= 918400u) return;
    unsigned int e = t * 8u;
    const float* src; unsigned int idx; unsigned short* dst; float scale = 1.0f;
    if (e < 4194304u)      { src = seq; idx = e;            dst = ws + 12582912u; }
    else if (e < 5242880u) { src = wq;  idx = e - 4194304u; dst = ws + 16777216u; }
    else if (e < 6291456u) { src = wk;  idx = e - 5242880u; dst = ws + 17825792u; }
    else if (e < 7340032u) { src = wv;  idx = e - 6291456u; dst = ws + 18874368u; }
    else if (e < 7341056u) { src = bq;  idx = e - 7340032u; dst = ws + 20971520u; }
    else if (e < 7342080u) { src = bk;  idx = e - 7341056u; dst = ws + 20972544u; }
    else if (e < 7343104u) { src = bv;  idx = e - 7342080u; dst = ws + 20973568u; }
    else { src = pm; idx = e - 7343104u; dst = ws + 20974592u; scale = 1.4426950f; }
    float4 a = *(const float4*)(src + idx);
    float4 c = *(const float4*)(src + idx + 4);
    uint4 st;
    st.x = (unsigned)f2bf(a.x * scale) | ((unsigned)f2bf(a.y * scale) << 16);
    st.y = (unsigned)f2bf(a.z * scale) | ((unsigned)f2bf(a.w * scale) << 16);
    st.z = (unsigned)f2bf(c.x * scale) | ((unsigned)f2bf(c.y * scale) << 16);
    st.w = (unsigned)f2bf(c.z * scale) | ((unsigned)f2bf(c.w * scale) << 16);
    *(uint4*)(dst + idx) = st;
}

// ---------------- QKV projection (R7, unchanged: 48.6 us, 0 conflicts) -------------
__global__ __launch_bounds__(256) void qkv_proj(
    const unsigned short* __restrict__ X,
    const unsigned short* __restrict__ Wq, const unsigned short* __restrict__ bq,
    const unsigned short* __restrict__ Wk, const unsigned short* __restrict__ bk,
    const unsigned short* __restrict__ Wv, const unsigned short* __restrict__ bv,
    unsigned short* __restrict__ dst_base)
{
    const int z = blockIdx.z;
    const unsigned short* W    = (z == 0) ? Wq : ((z == 1) ? Wk : Wv);
    const unsigned short* bias = (z == 0) ? bq : ((z == 1) ? bk : bv);
    const float osc = (z == 0) ? 0.18033688f : 1.0f;   // 0.125 * log2(e)
    unsigned short* dst = dst_base + (size_t)z * (4096u * 1024u);

    __shared__ __align__(16) unsigned short AsF[8192];   // [128 rows][64], col-swizzled
    __shared__ __align__(16) unsigned short BsF[8192];

    const int tid  = threadIdx.x;
    const int lane = tid & 63;
    const int wave = tid >> 6;
    const int quad = lane >> 4, r16 = lane & 15;
    const int wr = wave >> 1, wc = wave & 1;
    const int m0 = blockIdx.x * 128;
    const int n0 = blockIdx.y * 128;

    const int st_r3  = lane >> 3;
    const int st_col = ((lane & 7) ^ st_r3) << 3;

    floatx4 acc[4][4];
#pragma unroll
    for (int i = 0; i < 4; ++i)
#pragma unroll
        for (int j = 0; j < 4; ++j)
#pragma unroll
            for (int r = 0; r < 4; ++r) acc[i][j][r] = 0.f;

    for (int k0 = 0; k0 < 1024; k0 += 64) {
        __syncthreads();
#ifdef HAVE_GLL
#pragma unroll
        for (int c2 = 0; c2 < 4; ++c2) {
            int seg = wave * 4 + c2;
            int row = seg * 8 + st_r3;
            gll16(X + (size_t)(m0 + row) * 1024 + k0 + st_col, &AsF[seg * 512]);
            gll16(W + (size_t)(n0 + row) * 1024 + k0 + st_col, &BsF[seg * 512]);
        }
#else
#pragma unroll
        for (int c2 = 0; c2 < 4; ++c2) {
            int seg = wave * 4 + c2;
            int row = seg * 8 + st_r3;
            *(uint4*)&AsF[seg * 512 + lane * 8] = *(const uint4*)(X + (size_t)(m0 + row) * 1024 + k0 + st_col);
            *(uint4*)&BsF[seg * 512 + lane * 8] = *(const uint4*)(W + (size_t)(n0 + row) * 1024 + k0 + st_col);
        }
#endif
        __syncthreads();

#pragma unroll
        for (int kk = 0; kk < 2; ++kk) {
            const int csw = ((kk * 4 + quad) ^ (r16 & 7)) << 3;
            short8 a[4], b[4];
#pragma unroll
            for (int i = 0; i < 4; ++i)
                a[i] = *(const short8*)&AsF[(wr * 64 + i * 16 + r16) * 64 + csw];
#pragma unroll
            for (int j = 0; j < 4; ++j)
                b[j] = *(const short8*)&BsF[(wc * 64 + j * 16 + r16) * 64 + csw];
#pragma unroll
            for (int i = 0; i < 4; ++i)
#pragma unroll
                for (int j = 0; j < 4; ++j)
                    acc[i][j] = __builtin_amdgcn_mfma_f32_16x16x32_bf16(a[i], b[j], acc[i][j], 0, 0, 0);
        }
    }

#pragma unroll
    for (int j = 0; j < 4; ++j) {
        int n = n0 + wc * 64 + j * 16 + r16;
        float bvf = bf2f(bias[n]);
        int h = n >> 6, d = n & 63;
#pragma unroll
        for (int i = 0; i < 4; ++i) {
            int m_base = m0 + wr * 64 + i * 16 + quad * 4;
            int b = m_base >> 10, l0 = m_base & 1023;
            if (z == 2) {
                ushort4 st;
                st.x = f2bf(acc[i][j][0] + bvf); st.y = f2bf(acc[i][j][1] + bvf);
                st.z = f2bf(acc[i][j][2] + bvf); st.w = f2bf(acc[i][j][3] + bvf);
                *(ushort4*)&dst[(((size_t)(b * 16 + h)) * 64 + d) * 1024 + l0] = st;
            } else {
#pragma unroll
                for (int r = 0; r < 4; ++r)
                    dst[(((size_t)(b * 16 + h)) * 1024 + (l0 + r)) * 64 + d] =
                        f2bf((acc[i][j][r] + bvf) * osc);
            }
        }
    }
}

// ---------------- attention: barrier-free, direct-load K/V fragments ----------------
// grid (16, 64): blockIdx.x = 64-row q-tile, blockIdx.y = bh. 4 waves, each owns
// 16 q-rows. No __syncthreads; only wave-private P LDS round-trip.
__global__ __launch_bounds__(256) void attn(
    const unsigned short* __restrict__ Qw,     // (B,H,L,DH), pre-scaled by 0.125*log2e
    const unsigned short* __restrict__ Kw,     // (B,H,L,DH)
    const unsigned short* __restrict__ Vt_g,   // (B*H, DH, L)
    const unsigned short* __restrict__ pmask,  // (B,L), pre-scaled by log2e
    float* __restrict__ out)                   // (B,L,D) fp32
{
    __shared__ __align__(16) unsigned short PsF[4][2176];   // per wave: 16 rows x 136

    const int tid  = threadIdx.x;
    const int lane = tid & 63;
    const int wave = tid >> 6;
    const int quad = lane >> 4, r16 = lane & 15;

    const int qt = blockIdx.x;          // 0..15
    const int bh = blockIdx.y;          // 0..63
    const int b  = bh >> 4, h = bh & 15;
    const int q0 = qt * 64;

    const size_t base = (size_t)bh * (1024 * 64);
    const unsigned short* Qg = Qw + base;
    const unsigned short* Kg = Kw + base;
    const unsigned short* Vg = Vt_g + base;

    const int qrow = q0 + wave * 16 + r16;
    short8 aq0 = *(const short8*)(Qg + (size_t)qrow * 64 + quad * 8);
    short8 aq1 = *(const short8*)(Qg + (size_t)qrow * 64 + 32 + quad * 8);

    const int my_q = q0 + wave * 16 + quad * 4;

    float lsum[4];
    floatx4 o[4];
#pragma unroll
    for (int r = 0; r < 4; ++r) lsum[r] = 0.f;
#pragma unroll
    for (int j2 = 0; j2 < 4; ++j2)
#pragma unroll
        for (int r = 0; r < 4; ++r) o[j2][r] = 0.f;

    const int ktmax = qt >> 1;
    for (int kt = 0; kt <= ktmax; ++kt) {
        // K B-fragments direct from global: 16 consecutive rows x 64B per load
        short8 bk[8][2];
#pragma unroll
        for (int j = 0; j < 8; ++j)
#pragma unroll
            for (int kk = 0; kk < 2; ++kk)
                bk[j][kk] = *(const short8*)(Kg + (size_t)(kt * 128 + j * 16 + r16) * 64 + kk * 32 + quad * 8);

        floatx4 s[8];
#pragma unroll
        for (int j = 0; j < 8; ++j)
#pragma unroll
            for (int r = 0; r < 4; ++r) s[j][r] = 0.f;
#pragma unroll
        for (int j = 0; j < 8; ++j) {
            s[j] = __builtin_amdgcn_mfma_f32_16x16x32_bf16(aq0, bk[j][0], s[j], 0, 0, 0);
            s[j] = __builtin_amdgcn_mfma_f32_16x16x32_bf16(aq1, bk[j][1], s[j], 0, 0, 0);
        }

        // V B-fragments: issue now, consumed after softmax (latency hidden)
        short8 bv[4][4];
#pragma unroll
        for (int j2 = 0; j2 < 4; ++j2)
#pragma unroll
            for (int kk4 = 0; kk4 < 4; ++kk4)
                bv[j2][kk4] = *(const short8*)(Vg + (size_t)(j2 * 16 + r16) * 1024 + kt * 128 + kk4 * 32 + quad * 8);

        float pm2[8];
#pragma unroll
        for (int j = 0; j < 8; ++j)
            pm2[j] = bf2f(pmask[b * LL + kt * 128 + j * 16 + r16]) - 12.0f;  // fixed max

        if (kt == ktmax) {   // diagonal tile: causal mask (wave-uniform branch)
#pragma unroll
            for (int j = 0; j < 8; ++j) {
                int key = kt * 128 + j * 16 + r16;
#pragma unroll
                for (int r = 0; r < 4; ++r)
                    if (key > my_q + r) s[j][r] -= 1.0e9f;
            }
        }

        // fixed-max exp2 softmax; P -> wave-private LDS (row-major stride 136)
        asm volatile("s_waitcnt lgkmcnt(0)" ::: "memory");  // WAR: prior ap reads done
#pragma unroll
        for (int j = 0; j < 8; ++j) {
#pragma unroll
            for (int r = 0; r < 4; ++r) {
                float p = exp2f(s[j][r] + pm2[j]);
                lsum[r] += p;
                PsF[wave][(quad * 4 + r) * 136 + j * 16 + r16] = f2bf(p);
            }
        }
        asm volatile("s_waitcnt lgkmcnt(0)" ::: "memory");  // RAW: writes visible

#pragma unroll
        for (int kk4 = 0; kk4 < 4; ++kk4) {
            short8 ap = *(const short8*)&PsF[wave][r16 * 136 + kk4 * 32 + quad * 8];
#pragma unroll
            for (int j2 = 0; j2 < 4; ++j2)
                o[j2] = __builtin_amdgcn_mfma_f32_16x16x32_bf16(ap, bv[j2][kk4], o[j2], 0, 0, 0);
        }
    }

    // epilogue: l-reduce per row, normalize, store fp32
    float linv[4];
#pragma unroll
    for (int r = 0; r < 4; ++r) {
        float l = lsum[r];
        l += __shfl_xor(l, 1);
        l += __shfl_xor(l, 2);
        l += __shfl_xor(l, 4);
        l += __shfl_xor(l, 8);
        linv[r] = 1.0f / fmaxf(l, 1.0e-30f);
    }
#pragma unroll
    for (int j2 = 0; j2 < 4; ++j2) {
        int d = j2 * 16 + r16;
#pragma unroll
        for (int r = 0; r < 4; ++r) {
            size_t oidx = ((size_t)(b * 1024 + my_q + r)) * 1024 + h * 64 + d;
            out[oidx] = o[j2][r] * linv[r];
        }
    }
}

__global__ __launch_bounds__(256) void fill_sentinel_f(float* __restrict__ out,
                                                       float v, unsigned int n)
{
    unsigned int t = blockIdx.x * 256u + threadIdx.x;
    if (t < n) out[t] = v;
}

extern "C" void kernel_launch(void* const* d_in, const int* in_sizes, int n_in,
                              void* d_out, int out_size, void* d_ws, size_t ws_size,
                              hipStream_t stream) {
    bool sizes_ok = (n_in == 9) && in_sizes[0] == 4194304 && in_sizes[1] == 4096 &&
                    in_sizes[2] == 1048576 && in_sizes[3] == 1048576 && in_sizes[4] == 1024 &&
                    in_sizes[5] == 1048576 && in_sizes[6] == 1024 && in_sizes[7] == 1048576 &&
                    in_sizes[8] == 1024 && out_size == 4194304;
    if (!sizes_ok) {
        fill_sentinel_f<<<16384, 256, 0, stream>>>((float*)d_out, 100.0f, 4194304u);
        return;
    }
    if (ws_size < 50331652u) {
        fill_sentinel_f<<<16384, 256, 0, stream>>>((float*)d_out, 200.0f, 4194304u);
        return;
    }

    unsigned short* ws = (unsigned short*)d_ws;

    conv_in<<<3588, 256, 0, stream>>>(
        (const float*)d_in[0], (const float*)d_in[3], (const float*)d_in[5],
        (const float*)d_in[7], (const float*)d_in[4], (const float*)d_in[6],
        (const float*)d_in[8], (const float*)d_in[1], ws);

    const unsigned short* cseq = ws + 12582912u;
    const unsigned short* cwq  = ws + 16777216u;
    const unsigned short* cwk  = ws + 17825792u;
    const unsigned short* cwv  = ws + 18874368u;
    const unsigned short* cbq  = ws + 20971520u;
    const unsigned short* cbk  = ws + 20972544u;
    const unsigned short* cbv  = ws + 20973568u;
    const unsigned short* cpm  = ws + 20974592u;

    dim3 g1(32, 8, 3);
    qkv_proj<<<g1, 256, 0, stream>>>(cseq, cwq, cbq, cwk, cbk, cwv, cbv, ws);

    dim3 g2(16, 64);
    attn<<<g2, 256, 0, stream>>>(ws, ws + 4194304u, ws + 8388608u, cpm, (float*)d_out);
}

// Round 9
// 171.510 us; speedup vs baseline: 1.5398x; 1.5398x over previous
//
#include <hip/hip_runtime.h>
#include <hip/hip_bf16.h>

// B=4, L=1024, D=1024, H=16, DH=64. Inputs fp32 (proven R0-R4). Output fp32.
// Q pre-scaled by 0.125*log2(e) at proj; pmask pre-scaled by log2(e) at conv.
// Fixed-max exp2 softmax (m=12). R9 = R7 attn (LDS-staged, XOR-swizzled; R8's
// direct-load variant regressed 3x: dependency stalls, 16 lines/instr) +
// R8's x8-vectorized conv_in. ws elem offsets (bf16): Q[0,4M) K[4M,8M)
// V^T[8M,12M) seq@12582912 Wq@16777216 Wk@17825792 Wv@18874368
// bq@20971520 bk@20972544 bv@20973568 pm@20974592

#define LL 1024

typedef __attribute__((ext_vector_type(8))) short short8;
typedef __attribute__((ext_vector_type(4))) float floatx4;

__device__ __forceinline__ float bf2f(unsigned short u) {
    return __uint_as_float(((unsigned int)u) << 16);
}
__device__ __forceinline__ unsigned short f2bf(float f) {
    unsigned int x = __float_as_uint(f);
    unsigned int r = x + 0x7fffu + ((x >> 16) & 1u);
    return (unsigned short)(r >> 16);
}

#if __has_builtin(__builtin_amdgcn_global_load_lds)
#define HAVE_GLL 1
typedef __attribute__((address_space(1))) unsigned int as1_u32;
typedef __attribute__((address_space(3))) unsigned int as3_u32;
__device__ __forceinline__ void gll16(const void* g, void* l) {
    __builtin_amdgcn_global_load_lds((const as1_u32*)g, (as3_u32*)l, 16, 0, 0);
}
#endif

// ---- fp32 -> clean bf16 conversion, vectorized x8 ----
__global__ __launch_bounds__(256) void conv_in(
    const float* __restrict__ seq, const float* __restrict__ wq,
    const float* __restrict__ wk,  const float* __restrict__ wv,
    const float* __restrict__ bq,  const float* __restrict__ bk,
    const float* __restrict__ bv,  const float* __restrict__ pm,
    unsigned short* __restrict__ ws)
{
    unsigned int t = blockIdx.x * 256u + threadIdx.x;   // grid 3588 -> 918,400 x8
    if (t >= 918400u) return;
    unsigned int e = t * 8u;
    const float* src; unsigned int idx; unsigned short* dst; float scale = 1.0f;
    if (e < 4194304u)      { src = seq; idx = e;            dst = ws + 12582912u; }
    else if (e < 5242880u) { src = wq;  idx = e - 4194304u; dst = ws + 16777216u; }
    else if (e < 6291456u) { src = wk;  idx = e - 5242880u; dst = ws + 17825792u; }
    else if (e < 7340032u) { src = wv;  idx = e - 6291456u; dst = ws + 18874368u; }
    else if (e < 7341056u) { src = bq;  idx = e - 7340032u; dst = ws + 20971520u; }
    else if (e < 7342080u) { src = bk;  idx = e - 7341056u; dst = ws + 20972544u; }
    else if (e < 7343104u) { src = bv;  idx = e - 7342080u; dst = ws + 20973568u; }
    else { src = pm; idx = e - 7343104u; dst = ws + 20974592u; scale = 1.4426950f; }
    float4 a = *(const float4*)(src + idx);
    float4 c = *(const float4*)(src + idx + 4);
    uint4 st;
    st.x = (unsigned)f2bf(a.x * scale) | ((unsigned)f2bf(a.y * scale) << 16);
    st.y = (unsigned)f2bf(a.z * scale) | ((unsigned)f2bf(a.w * scale) << 16);
    st.z = (unsigned)f2bf(c.x * scale) | ((unsigned)f2bf(c.y * scale) << 16);
    st.w = (unsigned)f2bf(c.z * scale) | ((unsigned)f2bf(c.w * scale) << 16);
    *(uint4*)(dst + idx) = st;
}

// ---------------- QKV projection (R7, unchanged: 48.6 us, 0 conflicts) -------------
__global__ __launch_bounds__(256) void qkv_proj(
    const unsigned short* __restrict__ X,
    const unsigned short* __restrict__ Wq, const unsigned short* __restrict__ bq,
    const unsigned short* __restrict__ Wk, const unsigned short* __restrict__ bk,
    const unsigned short* __restrict__ Wv, const unsigned short* __restrict__ bv,
    unsigned short* __restrict__ dst_base)
{
    const int z = blockIdx.z;
    const unsigned short* W    = (z == 0) ? Wq : ((z == 1) ? Wk : Wv);
    const unsigned short* bias = (z == 0) ? bq : ((z == 1) ? bk : bv);
    const float osc = (z == 0) ? 0.18033688f : 1.0f;   // 0.125 * log2(e)
    unsigned short* dst = dst_base + (size_t)z * (4096u * 1024u);

    __shared__ __align__(16) unsigned short AsF[8192];   // [128 rows][64], col-swizzled
    __shared__ __align__(16) unsigned short BsF[8192];

    const int tid  = threadIdx.x;
    const int lane = tid & 63;
    const int wave = tid >> 6;
    const int quad = lane >> 4, r16 = lane & 15;
    const int wr = wave >> 1, wc = wave & 1;
    const int m0 = blockIdx.x * 128;
    const int n0 = blockIdx.y * 128;

    const int st_r3  = lane >> 3;
    const int st_col = ((lane & 7) ^ st_r3) << 3;

    floatx4 acc[4][4];
#pragma unroll
    for (int i = 0; i < 4; ++i)
#pragma unroll
        for (int j = 0; j < 4; ++j)
#pragma unroll
            for (int r = 0; r < 4; ++r) acc[i][j][r] = 0.f;

    for (int k0 = 0; k0 < 1024; k0 += 64) {
        __syncthreads();
#ifdef HAVE_GLL
#pragma unroll
        for (int c2 = 0; c2 < 4; ++c2) {
            int seg = wave * 4 + c2;
            int row = seg * 8 + st_r3;
            gll16(X + (size_t)(m0 + row) * 1024 + k0 + st_col, &AsF[seg * 512]);
            gll16(W + (size_t)(n0 + row) * 1024 + k0 + st_col, &BsF[seg * 512]);
        }
#else
#pragma unroll
        for (int c2 = 0; c2 < 4; ++c2) {
            int seg = wave * 4 + c2;
            int row = seg * 8 + st_r3;
            *(uint4*)&AsF[seg * 512 + lane * 8] = *(const uint4*)(X + (size_t)(m0 + row) * 1024 + k0 + st_col);
            *(uint4*)&BsF[seg * 512 + lane * 8] = *(const uint4*)(W + (size_t)(n0 + row) * 1024 + k0 + st_col);
        }
#endif
        __syncthreads();

#pragma unroll
        for (int kk = 0; kk < 2; ++kk) {
            const int csw = ((kk * 4 + quad) ^ (r16 & 7)) << 3;
            short8 a[4], b[4];
#pragma unroll
            for (int i = 0; i < 4; ++i)
                a[i] = *(const short8*)&AsF[(wr * 64 + i * 16 + r16) * 64 + csw];
#pragma unroll
            for (int j = 0; j < 4; ++j)
                b[j] = *(const short8*)&BsF[(wc * 64 + j * 16 + r16) * 64 + csw];
#pragma unroll
            for (int i = 0; i < 4; ++i)
#pragma unroll
                for (int j = 0; j < 4; ++j)
                    acc[i][j] = __builtin_amdgcn_mfma_f32_16x16x32_bf16(a[i], b[j], acc[i][j], 0, 0, 0);
        }
    }

#pragma unroll
    for (int j = 0; j < 4; ++j) {
        int n = n0 + wc * 64 + j * 16 + r16;
        float bvf = bf2f(bias[n]);
        int h = n >> 6, d = n & 63;
#pragma unroll
        for (int i = 0; i < 4; ++i) {
            int m_base = m0 + wr * 64 + i * 16 + quad * 4;
            int b = m_base >> 10, l0 = m_base & 1023;
            if (z == 2) {
                ushort4 st;
                st.x = f2bf(acc[i][j][0] + bvf); st.y = f2bf(acc[i][j][1] + bvf);
                st.z = f2bf(acc[i][j][2] + bvf); st.w = f2bf(acc[i][j][3] + bvf);
                *(ushort4*)&dst[(((size_t)(b * 16 + h)) * 64 + d) * 1024 + l0] = st;
            } else {
#pragma unroll
                for (int r = 0; r < 4; ++r)
                    dst[(((size_t)(b * 16 + h)) * 1024 + (l0 + r)) * 64 + d] =
                        f2bf((acc[i][j][r] + bvf) * osc);
            }
        }
    }
}

// ---------------- fused flash attention (R7 verbatim: ~45 us) ----------------------
__global__ __launch_bounds__(256) void attn(
    const unsigned short* __restrict__ Qw,     // (B,H,L,DH), pre-scaled by 0.125*log2e
    const unsigned short* __restrict__ Kw,     // (B,H,L,DH)
    const unsigned short* __restrict__ Vt_g,   // (B*H, DH, L)
    const unsigned short* __restrict__ pmask,  // (B,L), pre-scaled by log2e
    float* __restrict__ out)                   // (B,L,D) fp32
{
    __shared__ __align__(16) unsigned short KsF[8192];      // [128 key][64 dh], swizzled
    __shared__ __align__(16) unsigned short VsF[8192];      // [64 dh][128 key], swizzled
    __shared__ __align__(16) unsigned short PsF[4][2048];   // per-wave, frag order

    const int tid  = threadIdx.x;
    const int lane = tid & 63;
    const int wave = tid >> 6;
    const int quad = lane >> 4, r16 = lane & 15;

    const int bid  = blockIdx.x;
    const int half = bid >> 8, rr = bid & 255;
    const int bh   = half * 32 + (rr >> 3);
    const int qi   = half ? (7 - (rr & 7)) : (rr & 7);
    const int b    = bh >> 4, h = bh & 15;
    const int q0   = qi << 7;

    const size_t base = (size_t)bh * (1024 * 64);
    const unsigned short* Qg = Qw + base;
    const unsigned short* Kg = Kw + base;
    const unsigned short* Vg = Vt_g + base;

    const int kst_r3  = lane >> 3;
    const int kst_col = ((lane & 7) ^ kst_r3) << 3;
    const int vst_r   = lane >> 4;

    short8 aq[2][2];
#pragma unroll
    for (int f = 0; f < 2; ++f) {
        int qrow = q0 + f * 64 + wave * 16 + r16;
        aq[f][0] = *(const short8*)(Qg + (size_t)qrow * 64 + quad * 8);
        aq[f][1] = *(const short8*)(Qg + (size_t)qrow * 64 + 32 + quad * 8);
    }

    float lsum[2][4];
    floatx4 o[2][4];
#pragma unroll
    for (int f = 0; f < 2; ++f)
#pragma unroll
        for (int r = 0; r < 4; ++r) lsum[f][r] = 0.f;
#pragma unroll
    for (int f = 0; f < 2; ++f)
#pragma unroll
        for (int j = 0; j < 4; ++j)
#pragma unroll
            for (int r = 0; r < 4; ++r) o[f][j][r] = 0.f;

    for (int kt = 0; kt <= qi; ++kt) {
        __syncthreads();
#ifdef HAVE_GLL
#pragma unroll
        for (int c2 = 0; c2 < 4; ++c2) {
            int seg = wave * 4 + c2;
            int krow = seg * 8 + kst_r3;
            gll16(Kg + (size_t)(kt * 128 + krow) * 64 + kst_col, &KsF[seg * 512]);
            int vrow = seg * 4 + vst_r;
            int vcol = (((lane & 15) ^ (vrow & 7))) << 3;
            gll16(Vg + (size_t)vrow * 1024 + kt * 128 + vcol, &VsF[seg * 512]);
        }
#else
#pragma unroll
        for (int c2 = 0; c2 < 4; ++c2) {
            int seg = wave * 4 + c2;
            int krow = seg * 8 + kst_r3;
            *(uint4*)&KsF[seg * 512 + lane * 8] =
                *(const uint4*)(Kg + (size_t)(kt * 128 + krow) * 64 + kst_col);
            int vrow = seg * 4 + vst_r;
            int vcol = (((lane & 15) ^ (vrow & 7))) << 3;
            *(uint4*)&VsF[seg * 512 + lane * 8] =
                *(const uint4*)(Vg + (size_t)vrow * 1024 + kt * 128 + vcol);
        }
#endif
        __syncthreads();

        float pm2[8];
#pragma unroll
        for (int j = 0; j < 8; ++j)
            pm2[j] = bf2f(pmask[b * LL + kt * 128 + j * 16 + r16]) - 12.0f;  // fixed max

#pragma unroll
        for (int f = 0; f < 2; ++f) {
            floatx4 s[8];
#pragma unroll
            for (int j = 0; j < 8; ++j)
#pragma unroll
                for (int r = 0; r < 4; ++r) s[j][r] = 0.f;
#pragma unroll
            for (int j = 0; j < 8; ++j) {
                short8 bk0 = *(const short8*)&KsF[(j * 16 + r16) * 64 + (((0 * 4 + quad) ^ (r16 & 7)) << 3)];
                s[j] = __builtin_amdgcn_mfma_f32_16x16x32_bf16(aq[f][0], bk0, s[j], 0, 0, 0);
                short8 bk1 = *(const short8*)&KsF[(j * 16 + r16) * 64 + (((1 * 4 + quad) ^ (r16 & 7)) << 3)];
                s[j] = __builtin_amdgcn_mfma_f32_16x16x32_bf16(aq[f][1], bk1, s[j], 0, 0, 0);
            }

            if (kt == qi) {   // diagonal tile: causal mask (wave-uniform branch)
                const int my_q = q0 + f * 64 + wave * 16 + quad * 4;
#pragma unroll
                for (int j = 0; j < 8; ++j) {
                    int key = kt * 128 + j * 16 + r16;
#pragma unroll
                    for (int r = 0; r < 4; ++r)
                        if (key > my_q + r) s[j][r] -= 1.0e9f;
                }
            }

            // fixed-max exp2 softmax + P into fragment-order LDS
            asm volatile("s_waitcnt lgkmcnt(0)" ::: "memory");  // WAR on PsF[wave]
#pragma unroll
            for (int j = 0; j < 8; ++j) {
                int key = j * 16 + r16;
                int ab = ((key >> 5) << 9) + (((key >> 3) & 3) << 7) + (key & 7) + (quad << 5);
#pragma unroll
                for (int r = 0; r < 4; ++r) {
                    float p = exp2f(s[j][r] + pm2[j]);
                    lsum[f][r] += p;
                    PsF[wave][ab + (r << 3)] = f2bf(p);
                }
            }
            asm volatile("s_waitcnt lgkmcnt(0)" ::: "memory");  // RAW on PsF[wave]

#pragma unroll
            for (int kk4 = 0; kk4 < 4; ++kk4) {
                short8 ap = *(const short8*)&PsF[wave][kk4 * 512 + lane * 8];
#pragma unroll
                for (int j2 = 0; j2 < 4; ++j2) {
                    short8 bv = *(const short8*)&VsF[(j2 * 16 + r16) * 128 + (((kk4 * 4 + quad) ^ (r16 & 7)) << 3)];
                    o[f][j2] = __builtin_amdgcn_mfma_f32_16x16x32_bf16(ap, bv, o[f][j2], 0, 0, 0);
                }
            }
        }
    }

    // epilogue: one l-reduction per row, then normalize + store fp32
#pragma unroll
    for (int f = 0; f < 2; ++f) {
        float linv[4];
#pragma unroll
        for (int r = 0; r < 4; ++r) {
            float l = lsum[f][r];
            l += __shfl_xor(l, 1);
            l += __shfl_xor(l, 2);
            l += __shfl_xor(l, 4);
            l += __shfl_xor(l, 8);
            linv[r] = 1.0f / fmaxf(l, 1.0e-30f);
        }
        const int my_q = q0 + f * 64 + wave * 16 + quad * 4;
#pragma unroll
        for (int j2 = 0; j2 < 4; ++j2) {
            int d = j2 * 16 + r16;
#pragma unroll
            for (int r = 0; r < 4; ++r) {
                size_t oidx = ((size_t)(b * 1024 + my_q + r)) * 1024 + h * 64 + d;
                out[oidx] = o[f][j2][r] * linv[r];
            }
        }
    }
}

__global__ __launch_bounds__(256) void fill_sentinel_f(float* __restrict__ out,
                                                       float v, unsigned int n)
{
    unsigned int t = blockIdx.x * 256u + threadIdx.x;
    if (t < n) out[t] = v;
}

extern "C" void kernel_launch(void* const* d_in, const int* in_sizes, int n_in,
                              void* d_out, int out_size, void* d_ws, size_t ws_size,
                              hipStream_t stream) {
    bool sizes_ok = (n_in == 9) && in_sizes[0] == 4194304 && in_sizes[1] == 4096 &&
                    in_sizes[2] == 1048576 && in_sizes[3] == 1048576 && in_sizes[4] == 1024 &&
                    in_sizes[5] == 1048576 && in_sizes[6] == 1024 && in_sizes[7] == 1048576 &&
                    in_sizes[8] == 1024 && out_size == 4194304;
    if (!sizes_ok) {
        fill_sentinel_f<<<16384, 256, 0, stream>>>((float*)d_out, 100.0f, 4194304u);
        return;
    }
    if (ws_size < 50331652u) {
        fill_sentinel_f<<<16384, 256, 0, stream>>>((float*)d_out, 200.0f, 4194304u);
        return;
    }

    unsigned short* ws = (unsigned short*)d_ws;

    conv_in<<<3588, 256, 0, stream>>>(
        (const float*)d_in[0], (const float*)d_in[3], (const float*)d_in[5],
        (const float*)d_in[7], (const float*)d_in[4], (const float*)d_in[6],
        (const float*)d_in[8], (const float*)d_in[1], ws);

    const unsigned short* cseq = ws + 12582912u;
    const unsigned short* cwq  = ws + 16777216u;
    const unsigned short* cwk  = ws + 17825792u;
    const unsigned short* cwv  = ws + 18874368u;
    const unsigned short* cbq  = ws + 20971520u;
    const unsigned short* cbk  = ws + 20972544u;
    const unsigned short* cbv  = ws + 20973568u;
    const unsigned short* cpm  = ws + 20974592u;

    dim3 g1(32, 8, 3);
    qkv_proj<<<g1, 256, 0, stream>>>(cseq, cwq, cbq, cwk, cbk, cwv, cbv, ws);

    attn<<<512, 256, 0, stream>>>(ws, ws + 4194304u, ws + 8388608u, cpm, (float*)d_out);
}

// Round 10
// 162.973 us; speedup vs baseline: 1.6205x; 1.0524x over previous
//
#include <hip/hip_runtime.h>
#include <hip/hip_bf16.h>

// B=4, L=1024, D=1024, H=16, DH=64. Inputs fp32 (proven R0-R4). Output fp32.
// Q pre-scaled by 0.125*log2(e) at proj; pmask pre-scaled by log2(e) at conv.
// Fixed-max exp2 softmax (m=12). R10 = R9 + attn VALU diet:
//   raw v_exp_f32 via __builtin_amdgcn_exp2f, truncating P->bf16 (error cancels
//   in softmax ratio), PsF double-buffer (WAR fence dropped: frag f+1's RAW
//   drain retires frag f's reads before parity reuse). LDS 64KB, 2 blocks/CU
//   (grid-capped anyway).
// ws elem offsets (bf16): Q[0,4M) K[4M,8M) V^T[8M,12M) seq@12582912
//   Wq@16777216 Wk@17825792 Wv@18874368 bq@20971520 bk@20972544 bv@20973568 pm@20974592

#define LL 1024

typedef __attribute__((ext_vector_type(8))) short short8;
typedef __attribute__((ext_vector_type(4))) float floatx4;

__device__ __forceinline__ float bf2f(unsigned short u) {
    return __uint_as_float(((unsigned int)u) << 16);
}
__device__ __forceinline__ unsigned short f2bf(float f) {
    unsigned int x = __float_as_uint(f);
    unsigned int r = x + 0x7fffu + ((x >> 16) & 1u);
    return (unsigned short)(r >> 16);
}

#if __has_builtin(__builtin_amdgcn_global_load_lds)
#define HAVE_GLL 1
typedef __attribute__((address_space(1))) unsigned int as1_u32;
typedef __attribute__((address_space(3))) unsigned int as3_u32;
__device__ __forceinline__ void gll16(const void* g, void* l) {
    __builtin_amdgcn_global_load_lds((const as1_u32*)g, (as3_u32*)l, 16, 0, 0);
}
#endif

#if __has_builtin(__builtin_amdgcn_exp2f)
#define EXP2F(x) __builtin_amdgcn_exp2f(x)
#else
#define EXP2F(x) exp2f(x)
#endif

// ---- fp32 -> clean bf16 conversion, vectorized x8 ----
__global__ __launch_bounds__(256) void conv_in(
    const float* __restrict__ seq, const float* __restrict__ wq,
    const float* __restrict__ wk,  const float* __restrict__ wv,
    const float* __restrict__ bq,  const float* __restrict__ bk,
    const float* __restrict__ bv,  const float* __restrict__ pm,
    unsigned short* __restrict__ ws)
{
    unsigned int t = blockIdx.x * 256u + threadIdx.x;   // grid 3588 -> 918,400 x8
    if (t >= 918400u) return;
    unsigned int e = t * 8u;
    const float* src; unsigned int idx; unsigned short* dst; float scale = 1.0f;
    if (e < 4194304u)      { src = seq; idx = e;            dst = ws + 12582912u; }
    else if (e < 5242880u) { src = wq;  idx = e - 4194304u; dst = ws + 16777216u; }
    else if (e < 6291456u) { src = wk;  idx = e - 5242880u; dst = ws + 17825792u; }
    else if (e < 7340032u) { src = wv;  idx = e - 6291456u; dst = ws + 18874368u; }
    else if (e < 7341056u) { src = bq;  idx = e - 7340032u; dst = ws + 20971520u; }
    else if (e < 7342080u) { src = bk;  idx = e - 7341056u; dst = ws + 20972544u; }
    else if (e < 7343104u) { src = bv;  idx = e - 7342080u; dst = ws + 20973568u; }
    else { src = pm; idx = e - 7343104u; dst = ws + 20974592u; scale = 1.4426950f; }
    float4 a = *(const float4*)(src + idx);
    float4 c = *(const float4*)(src + idx + 4);
    uint4 st;
    st.x = (unsigned)f2bf(a.x * scale) | ((unsigned)f2bf(a.y * scale) << 16);
    st.y = (unsigned)f2bf(a.z * scale) | ((unsigned)f2bf(a.w * scale) << 16);
    st.z = (unsigned)f2bf(c.x * scale) | ((unsigned)f2bf(c.y * scale) << 16);
    st.w = (unsigned)f2bf(c.z * scale) | ((unsigned)f2bf(c.w * scale) << 16);
    *(uint4*)(dst + idx) = st;
}

// ---------------- QKV projection (R7, unchanged: 48 us, 0 conflicts) ---------------
__global__ __launch_bounds__(256) void qkv_proj(
    const unsigned short* __restrict__ X,
    const unsigned short* __restrict__ Wq, const unsigned short* __restrict__ bq,
    const unsigned short* __restrict__ Wk, const unsigned short* __restrict__ bk,
    const unsigned short* __restrict__ Wv, const unsigned short* __restrict__ bv,
    unsigned short* __restrict__ dst_base)
{
    const int z = blockIdx.z;
    const unsigned short* W    = (z == 0) ? Wq : ((z == 1) ? Wk : Wv);
    const unsigned short* bias = (z == 0) ? bq : ((z == 1) ? bk : bv);
    const float osc = (z == 0) ? 0.18033688f : 1.0f;   // 0.125 * log2(e)
    unsigned short* dst = dst_base + (size_t)z * (4096u * 1024u);

    __shared__ __align__(16) unsigned short AsF[8192];   // [128 rows][64], col-swizzled
    __shared__ __align__(16) unsigned short BsF[8192];

    const int tid  = threadIdx.x;
    const int lane = tid & 63;
    const int wave = tid >> 6;
    const int quad = lane >> 4, r16 = lane & 15;
    const int wr = wave >> 1, wc = wave & 1;
    const int m0 = blockIdx.x * 128;
    const int n0 = blockIdx.y * 128;

    const int st_r3  = lane >> 3;
    const int st_col = ((lane & 7) ^ st_r3) << 3;

    floatx4 acc[4][4];
#pragma unroll
    for (int i = 0; i < 4; ++i)
#pragma unroll
        for (int j = 0; j < 4; ++j)
#pragma unroll
            for (int r = 0; r < 4; ++r) acc[i][j][r] = 0.f;

    for (int k0 = 0; k0 < 1024; k0 += 64) {
        __syncthreads();
#ifdef HAVE_GLL
#pragma unroll
        for (int c2 = 0; c2 < 4; ++c2) {
            int seg = wave * 4 + c2;
            int row = seg * 8 + st_r3;
            gll16(X + (size_t)(m0 + row) * 1024 + k0 + st_col, &AsF[seg * 512]);
            gll16(W + (size_t)(n0 + row) * 1024 + k0 + st_col, &BsF[seg * 512]);
        }
#else
#pragma unroll
        for (int c2 = 0; c2 < 4; ++c2) {
            int seg = wave * 4 + c2;
            int row = seg * 8 + st_r3;
            *(uint4*)&AsF[seg * 512 + lane * 8] = *(const uint4*)(X + (size_t)(m0 + row) * 1024 + k0 + st_col);
            *(uint4*)&BsF[seg * 512 + lane * 8] = *(const uint4*)(W + (size_t)(n0 + row) * 1024 + k0 + st_col);
        }
#endif
        __syncthreads();

#pragma unroll
        for (int kk = 0; kk < 2; ++kk) {
            const int csw = ((kk * 4 + quad) ^ (r16 & 7)) << 3;
            short8 a[4], b[4];
#pragma unroll
            for (int i = 0; i < 4; ++i)
                a[i] = *(const short8*)&AsF[(wr * 64 + i * 16 + r16) * 64 + csw];
#pragma unroll
            for (int j = 0; j < 4; ++j)
                b[j] = *(const short8*)&BsF[(wc * 64 + j * 16 + r16) * 64 + csw];
#pragma unroll
            for (int i = 0; i < 4; ++i)
#pragma unroll
                for (int j = 0; j < 4; ++j)
                    acc[i][j] = __builtin_amdgcn_mfma_f32_16x16x32_bf16(a[i], b[j], acc[i][j], 0, 0, 0);
        }
    }

#pragma unroll
    for (int j = 0; j < 4; ++j) {
        int n = n0 + wc * 64 + j * 16 + r16;
        float bvf = bf2f(bias[n]);
        int h = n >> 6, d = n & 63;
#pragma unroll
        for (int i = 0; i < 4; ++i) {
            int m_base = m0 + wr * 64 + i * 16 + quad * 4;
            int b = m_base >> 10, l0 = m_base & 1023;
            if (z == 2) {
                ushort4 st;
                st.x = f2bf(acc[i][j][0] + bvf); st.y = f2bf(acc[i][j][1] + bvf);
                st.z = f2bf(acc[i][j][2] + bvf); st.w = f2bf(acc[i][j][3] + bvf);
                *(ushort4*)&dst[(((size_t)(b * 16 + h)) * 64 + d) * 1024 + l0] = st;
            } else {
#pragma unroll
                for (int r = 0; r < 4; ++r)
                    dst[(((size_t)(b * 16 + h)) * 1024 + (l0 + r)) * 64 + d] =
                        f2bf((acc[i][j][r] + bvf) * osc);
            }
        }
    }
}

// ---------------- fused flash attention: R7 + VALU diet + PsF dbuf -----------------
__global__ __launch_bounds__(256) void attn(
    const unsigned short* __restrict__ Qw,     // (B,H,L,DH), pre-scaled by 0.125*log2e
    const unsigned short* __restrict__ Kw,     // (B,H,L,DH)
    const unsigned short* __restrict__ Vt_g,   // (B*H, DH, L)
    const unsigned short* __restrict__ pmask,  // (B,L), pre-scaled by log2e
    float* __restrict__ out)                   // (B,L,D) fp32
{
    __shared__ __align__(16) unsigned short KsF[8192];        // [128 key][64 dh], swizzled
    __shared__ __align__(16) unsigned short VsF[8192];        // [64 dh][128 key], swizzled
    __shared__ __align__(16) unsigned short PsF[2][4][2048];  // double-buffered, frag order

    const int tid  = threadIdx.x;
    const int lane = tid & 63;
    const int wave = tid >> 6;
    const int quad = lane >> 4, r16 = lane & 15;

    const int bid  = blockIdx.x;
    const int half = bid >> 8, rr = bid & 255;
    const int bh   = half * 32 + (rr >> 3);
    const int qi   = half ? (7 - (rr & 7)) : (rr & 7);
    const int b    = bh >> 4, h = bh & 15;
    const int q0   = qi << 7;

    const size_t base = (size_t)bh * (1024 * 64);
    const unsigned short* Qg = Qw + base;
    const unsigned short* Kg = Kw + base;
    const unsigned short* Vg = Vt_g + base;

    const int kst_r3  = lane >> 3;
    const int kst_col = ((lane & 7) ^ kst_r3) << 3;
    const int vst_r   = lane >> 4;

    short8 aq[2][2];
#pragma unroll
    for (int f = 0; f < 2; ++f) {
        int qrow = q0 + f * 64 + wave * 16 + r16;
        aq[f][0] = *(const short8*)(Qg + (size_t)qrow * 64 + quad * 8);
        aq[f][1] = *(const short8*)(Qg + (size_t)qrow * 64 + 32 + quad * 8);
    }

    float lsum[2][4];
    floatx4 o[2][4];
#pragma unroll
    for (int f = 0; f < 2; ++f)
#pragma unroll
        for (int r = 0; r < 4; ++r) lsum[f][r] = 0.f;
#pragma unroll
    for (int f = 0; f < 2; ++f)
#pragma unroll
        for (int j = 0; j < 4; ++j)
#pragma unroll
            for (int r = 0; r < 4; ++r) o[f][j][r] = 0.f;

    for (int kt = 0; kt <= qi; ++kt) {
        __syncthreads();
#ifdef HAVE_GLL
#pragma unroll
        for (int c2 = 0; c2 < 4; ++c2) {
            int seg = wave * 4 + c2;
            int krow = seg * 8 + kst_r3;
            gll16(Kg + (size_t)(kt * 128 + krow) * 64 + kst_col, &KsF[seg * 512]);
            int vrow = seg * 4 + vst_r;
            int vcol = (((lane & 15) ^ (vrow & 7))) << 3;
            gll16(Vg + (size_t)vrow * 1024 + kt * 128 + vcol, &VsF[seg * 512]);
        }
#else
#pragma unroll
        for (int c2 = 0; c2 < 4; ++c2) {
            int seg = wave * 4 + c2;
            int krow = seg * 8 + kst_r3;
            *(uint4*)&KsF[seg * 512 + lane * 8] =
                *(const uint4*)(Kg + (size_t)(kt * 128 + krow) * 64 + kst_col);
            int vrow = seg * 4 + vst_r;
            int vcol = (((lane & 15) ^ (vrow & 7))) << 3;
            *(uint4*)&VsF[seg * 512 + lane * 8] =
                *(const uint4*)(Vg + (size_t)vrow * 1024 + kt * 128 + vcol);
        }
#endif
        __syncthreads();

        float pm2[8];
#pragma unroll
        for (int j = 0; j < 8; ++j)
            pm2[j] = bf2f(pmask[b * LL + kt * 128 + j * 16 + r16]) - 12.0f;  // fixed max

#pragma unroll
        for (int f = 0; f < 2; ++f) {
            floatx4 s[8];
#pragma unroll
            for (int j = 0; j < 8; ++j)
#pragma unroll
                for (int r = 0; r < 4; ++r) s[j][r] = 0.f;
#pragma unroll
            for (int j = 0; j < 8; ++j) {
                short8 bk0 = *(const short8*)&KsF[(j * 16 + r16) * 64 + (((0 * 4 + quad) ^ (r16 & 7)) << 3)];
                s[j] = __builtin_amdgcn_mfma_f32_16x16x32_bf16(aq[f][0], bk0, s[j], 0, 0, 0);
                short8 bk1 = *(const short8*)&KsF[(j * 16 + r16) * 64 + (((1 * 4 + quad) ^ (r16 & 7)) << 3)];
                s[j] = __builtin_amdgcn_mfma_f32_16x16x32_bf16(aq[f][1], bk1, s[j], 0, 0, 0);
            }

            if (kt == qi) {   // diagonal tile: causal mask (wave-uniform branch)
                const int my_q = q0 + f * 64 + wave * 16 + quad * 4;
#pragma unroll
                for (int j = 0; j < 8; ++j) {
                    int key = kt * 128 + j * 16 + r16;
#pragma unroll
                    for (int r = 0; r < 4; ++r)
                        if (key > my_q + r) s[j][r] -= 1.0e9f;
                }
            }

            // fixed-max exp2 softmax; P -> PsF[f] (dbuf: no WAR fence needed —
            // frag f+1's RAW drain retires this frag's reads before parity reuse)
#pragma unroll
            for (int j = 0; j < 8; ++j) {
                int key = j * 16 + r16;
                int ab = ((key >> 5) << 9) + (((key >> 3) & 3) << 7) + (key & 7) + (quad << 5);
#pragma unroll
                for (int r = 0; r < 4; ++r) {
                    float p = EXP2F(s[j][r] + pm2[j]);
                    lsum[f][r] += p;
                    // truncating bf16 (1 VALU): error cancels in softmax ratio
                    PsF[f][wave][ab + (r << 3)] = (unsigned short)(__float_as_uint(p) >> 16);
                }
            }
            asm volatile("s_waitcnt lgkmcnt(0)" ::: "memory");  // RAW on PsF[f][wave]

#pragma unroll
            for (int kk4 = 0; kk4 < 4; ++kk4) {
                short8 ap = *(const short8*)&PsF[f][wave][kk4 * 512 + lane * 8];
#pragma unroll
                for (int j2 = 0; j2 < 4; ++j2) {
                    short8 bv = *(const short8*)&VsF[(j2 * 16 + r16) * 128 + (((kk4 * 4 + quad) ^ (r16 & 7)) << 3)];
                    o[f][j2] = __builtin_amdgcn_mfma_f32_16x16x32_bf16(ap, bv, o[f][j2], 0, 0, 0);
                }
            }
        }
    }

    // epilogue: one l-reduction per row, then normalize + store fp32
#pragma unroll
    for (int f = 0; f < 2; ++f) {
        float linv[4];
#pragma unroll
        for (int r = 0; r < 4; ++r) {
            float l = lsum[f][r];
            l += __shfl_xor(l, 1);
            l += __shfl_xor(l, 2);
            l += __shfl_xor(l, 4);
            l += __shfl_xor(l, 8);
            linv[r] = 1.0f / fmaxf(l, 1.0e-30f);
        }
        const int my_q = q0 + f * 64 + wave * 16 + quad * 4;
#pragma unroll
        for (int j2 = 0; j2 < 4; ++j2) {
            int d = j2 * 16 + r16;
#pragma unroll
            for (int r = 0; r < 4; ++r) {
                size_t oidx = ((size_t)(b * 1024 + my_q + r)) * 1024 + h * 64 + d;
                out[oidx] = o[f][j2][r] * linv[r];
            }
        }
    }
}

__global__ __launch_bounds__(256) void fill_sentinel_f(float* __restrict__ out,
                                                       float v, unsigned int n)
{
    unsigned int t = blockIdx.x * 256u + threadIdx.x;
    if (t < n) out[t] = v;
}

extern "C" void kernel_launch(void* const* d_in, const int* in_sizes, int n_in,
                              void* d_out, int out_size, void* d_ws, size_t ws_size,
                              hipStream_t stream) {
    bool sizes_ok = (n_in == 9) && in_sizes[0] == 4194304 && in_sizes[1] == 4096 &&
                    in_sizes[2] == 1048576 && in_sizes[3] == 1048576 && in_sizes[4] == 1024 &&
                    in_sizes[5] == 1048576 && in_sizes[6] == 1024 && in_sizes[7] == 1048576 &&
                    in_sizes[8] == 1024 && out_size == 4194304;
    if (!sizes_ok) {
        fill_sentinel_f<<<16384, 256, 0, stream>>>((float*)d_out, 100.0f, 4194304u);
        return;
    }
    if (ws_size < 50331652u) {
        fill_sentinel_f<<<16384, 256, 0, stream>>>((float*)d_out, 200.0f, 4194304u);
        return;
    }

    unsigned short* ws = (unsigned short*)d_ws;

    conv_in<<<3588, 256, 0, stream>>>(
        (const float*)d_in[0], (const float*)d_in[3], (const float*)d_in[5],
        (const float*)d_in[7], (const float*)d_in[4], (const float*)d_in[6],
        (const float*)d_in[8], (const float*)d_in[1], ws);

    const unsigned short* cseq = ws + 12582912u;
    const unsigned short* cwq  = ws + 16777216u;
    const unsigned short* cwk  = ws + 17825792u;
    const unsigned short* cwv  = ws + 18874368u;
    const unsigned short* cbq  = ws + 20971520u;
    const unsigned short* cbk  = ws + 20972544u;
    const unsigned short* cbv  = ws + 20973568u;
    const unsigned short* cpm  = ws + 20974592u;

    dim3 g1(32, 8, 3);
    qkv_proj<<<g1, 256, 0, stream>>>(cseq, cwq, cbq, cwk, cbk, cwv, cbv, ws);

    attn<<<512, 256, 0, stream>>>(ws, ws + 4194304u, ws + 8388608u, cpm, (float*)d_out);
}

// Round 11
// 158.585 us; speedup vs baseline: 1.6653x; 1.0277x over previous
//
#include <hip/hip_runtime.h>
#include <hip/hip_bf16.h>

// B=4, L=1024, D=1024, H=16, DH=64. Inputs fp32 (proven R0-R4). Output fp32.
// Q pre-scaled by 0.125*log2(e) at proj; pmask pre-scaled by log2(e) at conv.
// Fixed-max exp2 softmax (m=12). R11 = R10 + attn: (1) XCD-aware grid remap
// (bh in low bits -> same-bh blocks share an XCD's L2; complementary qi in high
// bits keeps CU pairs at 9 kt-tiles), (2) l-sum via MFMA ones-column (P*1),
// (3) pmask hoisted above the staging barrier.
// ws elem offsets (bf16): Q[0,4M) K[4M,8M) V^T[8M,12M) seq@12582912
//   Wq@16777216 Wk@17825792 Wv@18874368 bq@20971520 bk@20972544 bv@20973568 pm@20974592

#define LL 1024

typedef __attribute__((ext_vector_type(8))) short short8;
typedef __attribute__((ext_vector_type(4))) float floatx4;

__device__ __forceinline__ float bf2f(unsigned short u) {
    return __uint_as_float(((unsigned int)u) << 16);
}
__device__ __forceinline__ unsigned short f2bf(float f) {
    unsigned int x = __float_as_uint(f);
    unsigned int r = x + 0x7fffu + ((x >> 16) & 1u);
    return (unsigned short)(r >> 16);
}

#if __has_builtin(__builtin_amdgcn_global_load_lds)
#define HAVE_GLL 1
typedef __attribute__((address_space(1))) unsigned int as1_u32;
typedef __attribute__((address_space(3))) unsigned int as3_u32;
__device__ __forceinline__ void gll16(const void* g, void* l) {
    __builtin_amdgcn_global_load_lds((const as1_u32*)g, (as3_u32*)l, 16, 0, 0);
}
#endif

#if __has_builtin(__builtin_amdgcn_exp2f)
#define EXP2F(x) __builtin_amdgcn_exp2f(x)
#else
#define EXP2F(x) exp2f(x)
#endif

// ---- fp32 -> clean bf16 conversion, vectorized x8 ----
__global__ __launch_bounds__(256) void conv_in(
    const float* __restrict__ seq, const float* __restrict__ wq,
    const float* __restrict__ wk,  const float* __restrict__ wv,
    const float* __restrict__ bq,  const float* __restrict__ bk,
    const float* __restrict__ bv,  const float* __restrict__ pm,
    unsigned short* __restrict__ ws)
{
    unsigned int t = blockIdx.x * 256u + threadIdx.x;   // grid 3588 -> 918,400 x8
    if (t >= 918400u) return;
    unsigned int e = t * 8u;
    const float* src; unsigned int idx; unsigned short* dst; float scale = 1.0f;
    if (e < 4194304u)      { src = seq; idx = e;            dst = ws + 12582912u; }
    else if (e < 5242880u) { src = wq;  idx = e - 4194304u; dst = ws + 16777216u; }
    else if (e < 6291456u) { src = wk;  idx = e - 5242880u; dst = ws + 17825792u; }
    else if (e < 7340032u) { src = wv;  idx = e - 6291456u; dst = ws + 18874368u; }
    else if (e < 7341056u) { src = bq;  idx = e - 7340032u; dst = ws + 20971520u; }
    else if (e < 7342080u) { src = bk;  idx = e - 7341056u; dst = ws + 20972544u; }
    else if (e < 7343104u) { src = bv;  idx = e - 7342080u; dst = ws + 20973568u; }
    else { src = pm; idx = e - 7343104u; dst = ws + 20974592u; scale = 1.4426950f; }
    float4 a = *(const float4*)(src + idx);
    float4 c = *(const float4*)(src + idx + 4);
    uint4 st;
    st.x = (unsigned)f2bf(a.x * scale) | ((unsigned)f2bf(a.y * scale) << 16);
    st.y = (unsigned)f2bf(a.z * scale) | ((unsigned)f2bf(a.w * scale) << 16);
    st.z = (unsigned)f2bf(c.x * scale) | ((unsigned)f2bf(c.y * scale) << 16);
    st.w = (unsigned)f2bf(c.z * scale) | ((unsigned)f2bf(c.w * scale) << 16);
    *(uint4*)(dst + idx) = st;
}

// ---------------- QKV projection (R7, unchanged: 48 us, 0 conflicts) ---------------
__global__ __launch_bounds__(256) void qkv_proj(
    const unsigned short* __restrict__ X,
    const unsigned short* __restrict__ Wq, const unsigned short* __restrict__ bq,
    const unsigned short* __restrict__ Wk, const unsigned short* __restrict__ bk,
    const unsigned short* __restrict__ Wv, const unsigned short* __restrict__ bv,
    unsigned short* __restrict__ dst_base)
{
    const int z = blockIdx.z;
    const unsigned short* W    = (z == 0) ? Wq : ((z == 1) ? Wk : Wv);
    const unsigned short* bias = (z == 0) ? bq : ((z == 1) ? bk : bv);
    const float osc = (z == 0) ? 0.18033688f : 1.0f;   // 0.125 * log2(e)
    unsigned short* dst = dst_base + (size_t)z * (4096u * 1024u);

    __shared__ __align__(16) unsigned short AsF[8192];   // [128 rows][64], col-swizzled
    __shared__ __align__(16) unsigned short BsF[8192];

    const int tid  = threadIdx.x;
    const int lane = tid & 63;
    const int wave = tid >> 6;
    const int quad = lane >> 4, r16 = lane & 15;
    const int wr = wave >> 1, wc = wave & 1;
    const int m0 = blockIdx.x * 128;
    const int n0 = blockIdx.y * 128;

    const int st_r3  = lane >> 3;
    const int st_col = ((lane & 7) ^ st_r3) << 3;

    floatx4 acc[4][4];
#pragma unroll
    for (int i = 0; i < 4; ++i)
#pragma unroll
        for (int j = 0; j < 4; ++j)
#pragma unroll
            for (int r = 0; r < 4; ++r) acc[i][j][r] = 0.f;

    for (int k0 = 0; k0 < 1024; k0 += 64) {
        __syncthreads();
#ifdef HAVE_GLL
#pragma unroll
        for (int c2 = 0; c2 < 4; ++c2) {
            int seg = wave * 4 + c2;
            int row = seg * 8 + st_r3;
            gll16(X + (size_t)(m0 + row) * 1024 + k0 + st_col, &AsF[seg * 512]);
            gll16(W + (size_t)(n0 + row) * 1024 + k0 + st_col, &BsF[seg * 512]);
        }
#else
#pragma unroll
        for (int c2 = 0; c2 < 4; ++c2) {
            int seg = wave * 4 + c2;
            int row = seg * 8 + st_r3;
            *(uint4*)&AsF[seg * 512 + lane * 8] = *(const uint4*)(X + (size_t)(m0 + row) * 1024 + k0 + st_col);
            *(uint4*)&BsF[seg * 512 + lane * 8] = *(const uint4*)(W + (size_t)(n0 + row) * 1024 + k0 + st_col);
        }
#endif
        __syncthreads();

#pragma unroll
        for (int kk = 0; kk < 2; ++kk) {
            const int csw = ((kk * 4 + quad) ^ (r16 & 7)) << 3;
            short8 a[4], b[4];
#pragma unroll
            for (int i = 0; i < 4; ++i)
                a[i] = *(const short8*)&AsF[(wr * 64 + i * 16 + r16) * 64 + csw];
#pragma unroll
            for (int j = 0; j < 4; ++j)
                b[j] = *(const short8*)&BsF[(wc * 64 + j * 16 + r16) * 64 + csw];
#pragma unroll
            for (int i = 0; i < 4; ++i)
#pragma unroll
                for (int j = 0; j < 4; ++j)
                    acc[i][j] = __builtin_amdgcn_mfma_f32_16x16x32_bf16(a[i], b[j], acc[i][j], 0, 0, 0);
        }
    }

#pragma unroll
    for (int j = 0; j < 4; ++j) {
        int n = n0 + wc * 64 + j * 16 + r16;
        float bvf = bf2f(bias[n]);
        int h = n >> 6, d = n & 63;
#pragma unroll
        for (int i = 0; i < 4; ++i) {
            int m_base = m0 + wr * 64 + i * 16 + quad * 4;
            int b = m_base >> 10, l0 = m_base & 1023;
            if (z == 2) {
                ushort4 st;
                st.x = f2bf(acc[i][j][0] + bvf); st.y = f2bf(acc[i][j][1] + bvf);
                st.z = f2bf(acc[i][j][2] + bvf); st.w = f2bf(acc[i][j][3] + bvf);
                *(ushort4*)&dst[(((size_t)(b * 16 + h)) * 64 + d) * 1024 + l0] = st;
            } else {
#pragma unroll
                for (int r = 0; r < 4; ++r)
                    dst[(((size_t)(b * 16 + h)) * 1024 + (l0 + r)) * 64 + d] =
                        f2bf((acc[i][j][r] + bvf) * osc);
            }
        }
    }
}

// ---------------- fused flash attention: XCD-local, MFMA l-sum ---------------------
__global__ __launch_bounds__(256) void attn(
    const unsigned short* __restrict__ Qw,     // (B,H,L,DH), pre-scaled by 0.125*log2e
    const unsigned short* __restrict__ Kw,     // (B,H,L,DH)
    const unsigned short* __restrict__ Vt_g,   // (B*H, DH, L)
    const unsigned short* __restrict__ pmask,  // (B,L), pre-scaled by log2e
    float* __restrict__ out)                   // (B,L,D) fp32
{
    __shared__ __align__(16) unsigned short KsF[8192];        // [128 key][64 dh], swizzled
    __shared__ __align__(16) unsigned short VsF[8192];        // [64 dh][128 key], swizzled
    __shared__ __align__(16) unsigned short PsF[2][4][2048];  // double-buffered, frag order

    const int tid  = threadIdx.x;
    const int lane = tid & 63;
    const int wave = tid >> 6;
    const int quad = lane >> 4, r16 = lane & 15;

    // XCD-aware map: bh in low 6 bits (bid%8 == bh%8 -> same-bh blocks share an
    // XCD L2, 2MB working set); complementary qi in high bits (CU c pairs blocks
    // c and c+256: (qb)+(7-qb) -> uniform 9 kt-tiles/CU).
    const int bid  = blockIdx.x;
    const int half = bid >> 8, idx = bid & 255;
    const int bh   = idx & 63;
    const int qb   = idx >> 6;
    const int qi   = half ? (7 - qb) : qb;
    const int b    = bh >> 4, h = bh & 15;
    const int q0   = qi << 7;

    const size_t base = (size_t)bh * (1024 * 64);
    const unsigned short* Qg = Qw + base;
    const unsigned short* Kg = Kw + base;
    const unsigned short* Vg = Vt_g + base;

    const int kst_r3  = lane >> 3;
    const int kst_col = ((lane & 7) ^ kst_r3) << 3;
    const int vst_r   = lane >> 4;

    short8 aq[2][2];
#pragma unroll
    for (int f = 0; f < 2; ++f) {
        int qrow = q0 + f * 64 + wave * 16 + r16;
        aq[f][0] = *(const short8*)(Qg + (size_t)qrow * 64 + quad * 8);
        aq[f][1] = *(const short8*)(Qg + (size_t)qrow * 64 + 32 + quad * 8);
    }

    // constant all-1.0 bf16 B-fragment for l = P * ones (C-layout result: lane
    // (quad,r16) reg r holds l of row quad*4+r — no shuffles needed)
    short8 ones;
#pragma unroll
    for (int i = 0; i < 8; ++i) ones[i] = (short)0x3f80;

    floatx4 ol[2];     // l accumulators via MFMA
    floatx4 o[2][4];
#pragma unroll
    for (int f = 0; f < 2; ++f)
#pragma unroll
        for (int r = 0; r < 4; ++r) ol[f][r] = 0.f;
#pragma unroll
    for (int f = 0; f < 2; ++f)
#pragma unroll
        for (int j = 0; j < 4; ++j)
#pragma unroll
            for (int r = 0; r < 4; ++r) o[f][j][r] = 0.f;

    for (int kt = 0; kt <= qi; ++kt) {
        // pmask: independent global load issued before the barrier drain
        float pm2[8];
#pragma unroll
        for (int j = 0; j < 8; ++j)
            pm2[j] = bf2f(pmask[b * LL + kt * 128 + j * 16 + r16]) - 12.0f;  // fixed max

        __syncthreads();
#ifdef HAVE_GLL
#pragma unroll
        for (int c2 = 0; c2 < 4; ++c2) {
            int seg = wave * 4 + c2;
            int krow = seg * 8 + kst_r3;
            gll16(Kg + (size_t)(kt * 128 + krow) * 64 + kst_col, &KsF[seg * 512]);
            int vrow = seg * 4 + vst_r;
            int vcol = (((lane & 15) ^ (vrow & 7))) << 3;
            gll16(Vg + (size_t)vrow * 1024 + kt * 128 + vcol, &VsF[seg * 512]);
        }
#else
#pragma unroll
        for (int c2 = 0; c2 < 4; ++c2) {
            int seg = wave * 4 + c2;
            int krow = seg * 8 + kst_r3;
            *(uint4*)&KsF[seg * 512 + lane * 8] =
                *(const uint4*)(Kg + (size_t)(kt * 128 + krow) * 64 + kst_col);
            int vrow = seg * 4 + vst_r;
            int vcol = (((lane & 15) ^ (vrow & 7))) << 3;
            *(uint4*)&VsF[seg * 512 + lane * 8] =
                *(const uint4*)(Vg + (size_t)vrow * 1024 + kt * 128 + vcol);
        }
#endif
        __syncthreads();

#pragma unroll
        for (int f = 0; f < 2; ++f) {
            floatx4 s[8];
#pragma unroll
            for (int j = 0; j < 8; ++j)
#pragma unroll
                for (int r = 0; r < 4; ++r) s[j][r] = 0.f;
#pragma unroll
            for (int j = 0; j < 8; ++j) {
                short8 bk0 = *(const short8*)&KsF[(j * 16 + r16) * 64 + (((0 * 4 + quad) ^ (r16 & 7)) << 3)];
                s[j] = __builtin_amdgcn_mfma_f32_16x16x32_bf16(aq[f][0], bk0, s[j], 0, 0, 0);
                short8 bk1 = *(const short8*)&KsF[(j * 16 + r16) * 64 + (((1 * 4 + quad) ^ (r16 & 7)) << 3)];
                s[j] = __builtin_amdgcn_mfma_f32_16x16x32_bf16(aq[f][1], bk1, s[j], 0, 0, 0);
            }

            if (kt == qi) {   // diagonal tile: causal mask (wave-uniform branch)
                const int my_q = q0 + f * 64 + wave * 16 + quad * 4;
#pragma unroll
                for (int j = 0; j < 8; ++j) {
                    int key = kt * 128 + j * 16 + r16;
#pragma unroll
                    for (int r = 0; r < 4; ++r)
                        if (key > my_q + r) s[j][r] -= 1.0e9f;
                }
            }

            // fixed-max exp2 softmax; P -> PsF[f] (dbuf; truncating bf16)
#pragma unroll
            for (int j = 0; j < 8; ++j) {
                int key = j * 16 + r16;
                int ab = ((key >> 5) << 9) + (((key >> 3) & 3) << 7) + (key & 7) + (quad << 5);
#pragma unroll
                for (int r = 0; r < 4; ++r) {
                    float p = EXP2F(s[j][r] + pm2[j]);
                    PsF[f][wave][ab + (r << 3)] = (unsigned short)(__float_as_uint(p) >> 16);
                }
            }
            asm volatile("s_waitcnt lgkmcnt(0)" ::: "memory");  // RAW on PsF[f][wave]

#pragma unroll
            for (int kk4 = 0; kk4 < 4; ++kk4) {
                short8 ap = *(const short8*)&PsF[f][wave][kk4 * 512 + lane * 8];
                ol[f] = __builtin_amdgcn_mfma_f32_16x16x32_bf16(ap, ones, ol[f], 0, 0, 0);
#pragma unroll
                for (int j2 = 0; j2 < 4; ++j2) {
                    short8 bv = *(const short8*)&VsF[(j2 * 16 + r16) * 128 + (((kk4 * 4 + quad) ^ (r16 & 7)) << 3)];
                    o[f][j2] = __builtin_amdgcn_mfma_f32_16x16x32_bf16(ap, bv, o[f][j2], 0, 0, 0);
                }
            }
        }
    }

    // epilogue: l arrives in C-layout (lane already holds its 4 rows) — no shuffles
#pragma unroll
    for (int f = 0; f < 2; ++f) {
        float linv[4];
#pragma unroll
        for (int r = 0; r < 4; ++r)
            linv[r] = 1.0f / fmaxf(ol[f][r], 1.0e-30f);
        const int my_q = q0 + f * 64 + wave * 16 + quad * 4;
#pragma unroll
        for (int j2 = 0; j2 < 4; ++j2) {
            int d = j2 * 16 + r16;
#pragma unroll
            for (int r = 0; r < 4; ++r) {
                size_t oidx = ((size_t)(b * 1024 + my_q + r)) * 1024 + h * 64 + d;
                out[oidx] = o[f][j2][r] * linv[r];
            }
        }
    }
}

__global__ __launch_bounds__(256) void fill_sentinel_f(float* __restrict__ out,
                                                       float v, unsigned int n)
{
    unsigned int t = blockIdx.x * 256u + threadIdx.x;
    if (t < n) out[t] = v;
}

extern "C" void kernel_launch(void* const* d_in, const int* in_sizes, int n_in,
                              void* d_out, int out_size, void* d_ws, size_t ws_size,
                              hipStream_t stream) {
    bool sizes_ok = (n_in == 9) && in_sizes[0] == 4194304 && in_sizes[1] == 4096 &&
                    in_sizes[2] == 1048576 && in_sizes[3] == 1048576 && in_sizes[4] == 1024 &&
                    in_sizes[5] == 1048576 && in_sizes[6] == 1024 && in_sizes[7] == 1048576 &&
                    in_sizes[8] == 1024 && out_size == 4194304;
    if (!sizes_ok) {
        fill_sentinel_f<<<16384, 256, 0, stream>>>((float*)d_out, 100.0f, 4194304u);
        return;
    }
    if (ws_size < 50331652u) {
        fill_sentinel_f<<<16384, 256, 0, stream>>>((float*)d_out, 200.0f, 4194304u);
        return;
    }

    unsigned short* ws = (unsigned short*)d_ws;

    conv_in<<<3588, 256, 0, stream>>>(
        (const float*)d_in[0], (const float*)d_in[3], (const float*)d_in[5],
        (const float*)d_in[7], (const float*)d_in[4], (const float*)d_in[6],
        (const float*)d_in[8], (const float*)d_in[1], ws);

    const unsigned short* cseq = ws + 12582912u;
    const unsigned short* cwq  = ws + 16777216u;
    const unsigned short* cwk  = ws + 17825792u;
    const unsigned short* cwv  = ws + 18874368u;
    const unsigned short* cbq  = ws + 20971520u;
    const unsigned short* cbk  = ws + 20972544u;
    const unsigned short* cbv  = ws + 20973568u;
    const unsigned short* cpm  = ws + 20974592u;

    dim3 g1(32, 8, 3);
    qkv_proj<<<g1, 256, 0, stream>>>(cseq, cwq, cbq, cwk, cbk, cwv, cbv, ws);

    attn<<<512, 256, 0, stream>>>(ws, ws + 4194304u, ws + 8388608u, cpm, (float*)d_out);
}